// Round 1
// baseline (259.976 us; speedup 1.0000x reference)
//
#include <hip/hip_runtime.h>

typedef _Float16 half8 __attribute__((ext_vector_type(8)));
typedef _Float16 half4 __attribute__((ext_vector_type(4)));
typedef float f32x4 __attribute__((ext_vector_type(4)));

#define MFMA_F16 __builtin_amdgcn_mfma_f32_16x16x32_f16

constexpr int Bc = 2, Hc = 16, Sc = 2048, Dc = 64;
constexpr int QBLK = 64, KVBLK = 64;
constexpr int NQT = Sc / QBLK;  // 32
constexpr float LOG2E = 1.4426950408889634f;
constexpr float SCALE_LOG2E = 0.125f * LOG2E;  // 1/sqrt(64) * log2(e)
constexpr float NEGBIG = -1.0e9f;

__global__ __launch_bounds__(256, 2)
void sdpa_fwd(const float* __restrict__ Q, const float* __restrict__ K,
              const float* __restrict__ V, const float* __restrict__ AM,
              float* __restrict__ O)
{
    // LDS: K tile (fp16, padded), V tile transposed (fp16, padded),
    // additive key-mask (exp2 domain), per-wave P tile.
    __shared__ _Float16 Kh[KVBLK][Dc + 8];       // 9216 B
    __shared__ _Float16 Vt[Dc][KVBLK + 8];       // 9216 B  Vt[d][kv]
    __shared__ _Float16 Pl[4][16][KVBLK + 8];    // 9216 B  per-wave P
    __shared__ float    madd[KVBLK];

    const int bid = blockIdx.x;
    const int qt  = bid % NQT;
    const int bh  = bid / NQT;
    const int b   = bh / Hc;
    const int qb  = qt * QBLK;

    const int t    = threadIdx.x;
    const int w    = t >> 6;        // wave 0..3 -> q rows [qb+16w, qb+16w+16)
    const int lane = t & 63;
    const int l16  = lane & 15;
    const int hi   = lane >> 4;     // 0..3

    const size_t base = (size_t)bh * Sc * Dc;

    // ---- Q fragments, loaded once, scale*log2(e) folded in ----
    // A-frag for mfma 16x16x32: row = lane&15, k = (lane>>4)*8 + j (contiguous)
    half8 qfrag[2];
    {
        const float* qp = Q + base + (size_t)(qb + w * 16 + l16) * Dc;
        #pragma unroll
        for (int c = 0; c < 2; ++c) {
            const float* p = qp + c * 32 + hi * 8;
            #pragma unroll
            for (int j = 0; j < 8; ++j)
                qfrag[c][j] = (_Float16)(p[j] * SCALE_LOG2E);
        }
    }

    // ---- online-softmax state (per lane: 4 q-rows, row = hi*4 + r) ----
    f32x4 o[4];                       // o[dt] : C/D frag, col = dt*16 + l16
    float m[4], l[4];
    #pragma unroll
    for (int dt = 0; dt < 4; ++dt) o[dt] = (f32x4){0.f, 0.f, 0.f, 0.f};
    #pragma unroll
    for (int r = 0; r < 4; ++r) { m[r] = -INFINITY; l[r] = 0.f; }

    for (int kvt = 0; kvt <= qt; ++kvt) {
        const int kvb = kvt * KVBLK;

        // ---- cooperative stage: K -> Kh (fp16), V -> Vt (fp16 transposed) ----
        {
            const int r0 = t >> 4;          // 0..15
            const int d0 = (t & 15) * 4;    // 0..60
            #pragma unroll
            for (int i = 0; i < 4; ++i) {
                const int kv = r0 + i * 16;
                const size_t gofs = base + (size_t)(kvb + kv) * Dc + d0;
                float4 kf = *(const float4*)(K + gofs);
                half4 kh = { (_Float16)kf.x, (_Float16)kf.y,
                             (_Float16)kf.z, (_Float16)kf.w };
                *(half4*)(&Kh[kv][d0]) = kh;
                float4 vf = *(const float4*)(V + gofs);
                Vt[d0 + 0][kv] = (_Float16)vf.x;
                Vt[d0 + 1][kv] = (_Float16)vf.y;
                Vt[d0 + 2][kv] = (_Float16)vf.z;
                Vt[d0 + 3][kv] = (_Float16)vf.w;
            }
            if (t < KVBLK)
                madd[t] = (1.0f - AM[(size_t)b * Sc + kvb + t]) * (NEGBIG * LOG2E);
        }
        __syncthreads();

        // ---- S = (Q*scale*log2e) . K^T  (exp2 domain logits) ----
        // D-frag: col(key) = l16 within nt-subtile, row(q) = hi*4 + r
        f32x4 s[4];
        #pragma unroll
        for (int nt = 0; nt < 4; ++nt) {
            s[nt] = (f32x4){0.f, 0.f, 0.f, 0.f};
            #pragma unroll
            for (int c = 0; c < 2; ++c) {
                half8 kf = *(const half8*)(&Kh[nt * 16 + l16][c * 32 + hi * 8]);
                s[nt] = MFMA_F16(qfrag[c], kf, s[nt], 0, 0, 0);
            }
        }

        // ---- masks ----
        const bool diag = (kvt == qt);
        #pragma unroll
        for (int nt = 0; nt < 4; ++nt) {
            const int key = kvb + nt * 16 + l16;
            const float ma = madd[nt * 16 + l16];
            #pragma unroll
            for (int r = 0; r < 4; ++r) {
                float v = s[nt][r] + ma;
                if (diag && key > (qb + w * 16 + hi * 4 + r)) v = NEGBIG;
                s[nt][r] = v;
            }
        }

        // ---- online softmax (wave-parallel; reduce across l16 group) ----
        float pm[4];
        #pragma unroll
        for (int r = 0; r < 4; ++r)
            pm[r] = fmaxf(fmaxf(s[0][r], s[1][r]), fmaxf(s[2][r], s[3][r]));
        #pragma unroll
        for (int r = 0; r < 4; ++r) {
            pm[r] = fmaxf(pm[r], __shfl_xor(pm[r], 1));
            pm[r] = fmaxf(pm[r], __shfl_xor(pm[r], 2));
            pm[r] = fmaxf(pm[r], __shfl_xor(pm[r], 4));
            pm[r] = fmaxf(pm[r], __shfl_xor(pm[r], 8));
        }
        float rs[4];
        #pragma unroll
        for (int r = 0; r < 4; ++r) {
            const float mn = fmaxf(m[r], pm[r]);
            const float f  = exp2f(m[r] - mn);   // first iter: exp2(-inf)=0
            m[r] = mn;
            l[r] *= f;
            #pragma unroll
            for (int dt = 0; dt < 4; ++dt) o[dt][r] *= f;
            rs[r] = 0.f;
        }
        #pragma unroll
        for (int nt = 0; nt < 4; ++nt) {
            #pragma unroll
            for (int r = 0; r < 4; ++r) {
                const float p = exp2f(s[nt][r] - m[r]);
                rs[r] += p;
                Pl[w][hi * 4 + r][nt * 16 + l16] = (_Float16)p;
            }
        }
        #pragma unroll
        for (int r = 0; r < 4; ++r) {
            rs[r] += __shfl_xor(rs[r], 1);
            rs[r] += __shfl_xor(rs[r], 2);
            rs[r] += __shfl_xor(rs[r], 4);
            rs[r] += __shfl_xor(rs[r], 8);
            l[r] += rs[r];
        }

        // ---- O += P . V  (wave-private P via LDS re-fragmentation) ----
        // A-frag: row(q) = l16, k(kv) = c*32 + hi*8 + j
        half8 pf0 = *(const half8*)(&Pl[w][l16][hi * 8]);
        half8 pf1 = *(const half8*)(&Pl[w][l16][32 + hi * 8]);
        #pragma unroll
        for (int dt = 0; dt < 4; ++dt) {
            half8 vf0 = *(const half8*)(&Vt[dt * 16 + l16][hi * 8]);
            half8 vf1 = *(const half8*)(&Vt[dt * 16 + l16][32 + hi * 8]);
            o[dt] = MFMA_F16(pf0, vf0, o[dt], 0, 0, 0);
            o[dt] = MFMA_F16(pf1, vf1, o[dt], 0, 0, 0);
        }
        __syncthreads();   // protect Kh/Vt before next stage
    }

    // ---- epilogue: normalize and store ----
    const int qrow0 = qb + w * 16 + hi * 4;
    float* op = O + base;
    #pragma unroll
    for (int r = 0; r < 4; ++r) {
        const float inv = 1.0f / l[r];
        #pragma unroll
        for (int dt = 0; dt < 4; ++dt)
            op[(size_t)(qrow0 + r) * Dc + dt * 16 + l16] = o[dt][r] * inv;
    }
}

extern "C" void kernel_launch(void* const* d_in, const int* in_sizes, int n_in,
                              void* d_out, int out_size, void* d_ws, size_t ws_size,
                              hipStream_t stream)
{
    const float* q  = (const float*)d_in[0];
    const float* k  = (const float*)d_in[1];
    const float* v  = (const float*)d_in[2];
    const float* am = (const float*)d_in[3];
    float* out = (float*)d_out;

    dim3 grid(Bc * Hc * NQT);   // 1024 blocks: qt fastest, bh slow
    sdpa_fwd<<<grid, 256, 0, stream>>>(q, k, v, am, out);
}

// Round 2
// 166.378 us; speedup vs baseline: 1.5626x; 1.5626x over previous
//
#include <hip/hip_runtime.h>

typedef _Float16 half8 __attribute__((ext_vector_type(8)));
typedef _Float16 half4 __attribute__((ext_vector_type(4)));
typedef float f32x4 __attribute__((ext_vector_type(4)));

#define MFMA_F16 __builtin_amdgcn_mfma_f32_16x16x32_f16

constexpr int Bc = 2, Hc = 16, Sc = 2048, Dc = 64;
constexpr int QBLK = 64, KVBLK = 64;
constexpr int NQT = Sc / QBLK;   // 32
constexpr int NPAIR = NQT / 2;   // 16
constexpr float LOG2E = 1.4426950408889634f;
constexpr float SCALE_LOG2E = 0.125f * LOG2E;  // 1/sqrt(64) * log2(e)
constexpr float NEGBIG = -1.0e9f;

__global__ __launch_bounds__(256, 2)
void sdpa_fwd(const float* __restrict__ Q, const float* __restrict__ K,
              const float* __restrict__ V, const float* __restrict__ AM,
              float* __restrict__ O)
{
    __shared__ _Float16 Kh[KVBLK][Dc + 8];       // 9216 B
    __shared__ _Float16 Vt[Dc][KVBLK + 8];       // 9216 B  Vt[d][kv]
    __shared__ _Float16 Pl[4][16][KVBLK + 8];    // 9216 B  per-wave P
    __shared__ float    madd[KVBLK];

    // 512 blocks. Bijective XCD chunk swizzle (nwg%8==0): each XCD gets 64
    // consecutive logical ids -> 4 bh values share K/V in that XCD's L2.
    const int bid = blockIdx.x;
    const int lid = (bid & 7) * 64 + (bid >> 3);
    const int bh  = lid >> 4;      // 0..31
    const int p   = lid & 15;      // causal pair index 0..15
    const int b   = bh / Hc;

    const int t    = threadIdx.x;
    const int w    = t >> 6;
    const int lane = t & 63;
    const int l16  = lane & 15;
    const int hi   = lane >> 4;

    const size_t base = (size_t)bh * Sc * Dc;

    // staging assignment: thread -> (kv = skv+16i, d = sd0..sd0+3)
    // V-transpose stores land 2 lanes/bank (free), K stores 2-way.
    const int sd0 = (t >> 4) * 4;   // 0..60
    const int skv = t & 15;

    float4 kreg[4], vreg[4];
    float  amreg = 0.f;

    // process causal pair {p, 31-p}: constant 33 kv-tiles per block
    #pragma unroll 1
    for (int mbr = 0; mbr < 2; ++mbr) {
        const int qt  = (mbr == 0) ? p : (NQT - 1 - p);
        const int qb  = qt * QBLK;
        const int nkv = qt + 1;

        // ---- Q fragments (scale*log2e folded) ----
        half8 qfrag[2];
        {
            const float* qp = Q + base + (size_t)(qb + w * 16 + l16) * Dc;
            #pragma unroll
            for (int c = 0; c < 2; ++c) {
                const float* pq = qp + c * 32 + hi * 8;
                #pragma unroll
                for (int j = 0; j < 8; ++j)
                    qfrag[c][j] = (_Float16)(pq[j] * SCALE_LOG2E);
            }
        }

        f32x4 o[4];
        float m[4], l[4];
        #pragma unroll
        for (int dt = 0; dt < 4; ++dt) o[dt] = (f32x4){0.f, 0.f, 0.f, 0.f};
        #pragma unroll
        for (int r = 0; r < 4; ++r) { m[r] = -INFINITY; l[r] = 0.f; }

        // ---- stage tile 0 ----
        #pragma unroll
        for (int i = 0; i < 4; ++i) {
            const size_t gofs = base + (size_t)(skv + 16 * i) * Dc + sd0;
            kreg[i] = *(const float4*)(K + gofs);
            vreg[i] = *(const float4*)(V + gofs);
        }
        if (t < KVBLK) amreg = AM[(size_t)b * Sc + t];
        // (for mbr==1 the loop's trailing barrier already protects LDS)
        #pragma unroll
        for (int i = 0; i < 4; ++i) {
            const int kv = skv + 16 * i;
            half4 kh = { (_Float16)kreg[i].x, (_Float16)kreg[i].y,
                         (_Float16)kreg[i].z, (_Float16)kreg[i].w };
            *(half4*)(&Kh[kv][sd0]) = kh;
            Vt[sd0 + 0][kv] = (_Float16)vreg[i].x;
            Vt[sd0 + 1][kv] = (_Float16)vreg[i].y;
            Vt[sd0 + 2][kv] = (_Float16)vreg[i].z;
            Vt[sd0 + 3][kv] = (_Float16)vreg[i].w;
        }
        if (t < KVBLK) madd[t] = (1.0f - amreg) * (NEGBIG * LOG2E);
        __syncthreads();

        for (int kvt = 0; kvt < nkv; ++kvt) {
            const int kvb  = kvt * KVBLK;
            const bool pref = (kvt + 1 < nkv);

            // ---- prefetch next tile into registers (hidden under compute) ----
            if (pref) {
                const int nkvb = kvb + KVBLK;
                #pragma unroll
                for (int i = 0; i < 4; ++i) {
                    const size_t gofs = base + (size_t)(nkvb + skv + 16 * i) * Dc + sd0;
                    kreg[i] = *(const float4*)(K + gofs);
                    vreg[i] = *(const float4*)(V + gofs);
                }
                if (t < KVBLK) amreg = AM[(size_t)b * Sc + nkvb + t];
            }

            // ---- S = (Q*scale*log2e) . K^T ----
            f32x4 s[4];
            #pragma unroll
            for (int nt = 0; nt < 4; ++nt) {
                s[nt] = (f32x4){0.f, 0.f, 0.f, 0.f};
                #pragma unroll
                for (int c = 0; c < 2; ++c) {
                    half8 kf = *(const half8*)(&Kh[nt * 16 + l16][c * 32 + hi * 8]);
                    s[nt] = MFMA_F16(qfrag[c], kf, s[nt], 0, 0, 0);
                }
            }

            // ---- masks ----
            const bool diag = (kvt == qt);
            const int qrow = qb + w * 16 + hi * 4;
            #pragma unroll
            for (int nt = 0; nt < 4; ++nt) {
                const int key = kvb + nt * 16 + l16;
                const float ma = madd[nt * 16 + l16];
                #pragma unroll
                for (int r = 0; r < 4; ++r) {
                    float v = s[nt][r] + ma;
                    if (diag && key > qrow + r) v = NEGBIG;
                    s[nt][r] = v;
                }
            }

            // ---- online softmax (wave-parallel over l16 group) ----
            float pm[4];
            #pragma unroll
            for (int r = 0; r < 4; ++r)
                pm[r] = fmaxf(fmaxf(s[0][r], s[1][r]), fmaxf(s[2][r], s[3][r]));
            #pragma unroll
            for (int r = 0; r < 4; ++r) {
                pm[r] = fmaxf(pm[r], __shfl_xor(pm[r], 1));
                pm[r] = fmaxf(pm[r], __shfl_xor(pm[r], 2));
                pm[r] = fmaxf(pm[r], __shfl_xor(pm[r], 4));
                pm[r] = fmaxf(pm[r], __shfl_xor(pm[r], 8));
            }
            float rs[4];
            #pragma unroll
            for (int r = 0; r < 4; ++r) {
                const float mn = fmaxf(m[r], pm[r]);
                const float f  = exp2f(m[r] - mn);
                m[r] = mn;
                l[r] *= f;
                #pragma unroll
                for (int dt = 0; dt < 4; ++dt) o[dt][r] *= f;
                rs[r] = 0.f;
            }
            #pragma unroll
            for (int nt = 0; nt < 4; ++nt) {
                #pragma unroll
                for (int r = 0; r < 4; ++r) {
                    const float pv = exp2f(s[nt][r] - m[r]);
                    rs[r] += pv;
                    Pl[w][hi * 4 + r][nt * 16 + l16] = (_Float16)pv;
                }
            }
            #pragma unroll
            for (int r = 0; r < 4; ++r) {
                rs[r] += __shfl_xor(rs[r], 1);
                rs[r] += __shfl_xor(rs[r], 2);
                rs[r] += __shfl_xor(rs[r], 4);
                rs[r] += __shfl_xor(rs[r], 8);
                l[r] += rs[r];
            }

            // ---- O += P . V ----
            half8 pf0 = *(const half8*)(&Pl[w][l16][hi * 8]);
            half8 pf1 = *(const half8*)(&Pl[w][l16][32 + hi * 8]);
            #pragma unroll
            for (int dt = 0; dt < 4; ++dt) {
                half8 vf0 = *(const half8*)(&Vt[dt * 16 + l16][hi * 8]);
                half8 vf1 = *(const half8*)(&Vt[dt * 16 + l16][32 + hi * 8]);
                o[dt] = MFMA_F16(pf0, vf0, o[dt], 0, 0, 0);
                o[dt] = MFMA_F16(pf1, vf1, o[dt], 0, 0, 0);
            }
            __syncthreads();   // all waves done reading Kh/Vt

            // ---- write prefetched tile to LDS ----
            if (pref) {
                #pragma unroll
                for (int i = 0; i < 4; ++i) {
                    const int kv = skv + 16 * i;
                    half4 kh = { (_Float16)kreg[i].x, (_Float16)kreg[i].y,
                                 (_Float16)kreg[i].z, (_Float16)kreg[i].w };
                    *(half4*)(&Kh[kv][sd0]) = kh;
                    Vt[sd0 + 0][kv] = (_Float16)vreg[i].x;
                    Vt[sd0 + 1][kv] = (_Float16)vreg[i].y;
                    Vt[sd0 + 2][kv] = (_Float16)vreg[i].z;
                    Vt[sd0 + 3][kv] = (_Float16)vreg[i].w;
                }
                if (t < KVBLK) madd[t] = (1.0f - amreg) * (NEGBIG * LOG2E);
                __syncthreads();
            }
        }

        // ---- epilogue ----
        const int qrow0 = qb + w * 16 + hi * 4;
        float* op = O + base;
        #pragma unroll
        for (int r = 0; r < 4; ++r) {
            const float inv = 1.0f / l[r];
            #pragma unroll
            for (int dt = 0; dt < 4; ++dt)
                op[(size_t)(qrow0 + r) * Dc + dt * 16 + l16] = o[dt][r] * inv;
        }
    }
}

extern "C" void kernel_launch(void* const* d_in, const int* in_sizes, int n_in,
                              void* d_out, int out_size, void* d_ws, size_t ws_size,
                              hipStream_t stream)
{
    const float* q  = (const float*)d_in[0];
    const float* k  = (const float*)d_in[1];
    const float* v  = (const float*)d_in[2];
    const float* am = (const float*)d_in[3];
    float* out = (float*)d_out;

    dim3 grid(Bc * Hc * NPAIR);   // 512 uniform-work blocks
    sdpa_fwd<<<grid, 256, 0, stream>>>(q, k, v, am, out);
}

// Round 3
// 143.936 us; speedup vs baseline: 1.8062x; 1.1559x over previous
//
#include <hip/hip_runtime.h>

typedef _Float16 half8 __attribute__((ext_vector_type(8)));
typedef _Float16 half4 __attribute__((ext_vector_type(4)));
typedef float f32x4 __attribute__((ext_vector_type(4)));

#define MFMA_F16 __builtin_amdgcn_mfma_f32_16x16x32_f16

constexpr int Bc = 2, Hc = 16, Sc = 2048, Dc = 64;
constexpr int QBLK = 64, KVBLK = 64;
constexpr int NQT = Sc / QBLK;            // 32
constexpr float LOG2E = 1.4426950408889634f;
constexpr float SCALE_LOG2E = 0.125f * LOG2E;  // 1/sqrt(64) * log2(e)
constexpr float NEGBIG = -1.0e9f;
constexpr int LDK = 72;                   // f16 row stride for Kh/Vt
constexpr float DEFER_THR = 11.0f;        // defer-max threshold (log2 units ~ 7.6 nats)

__global__ __launch_bounds__(256, 4)
void sdpa_fwd(const float* __restrict__ Q, const float* __restrict__ K,
              const float* __restrict__ V, const float* __restrict__ AM,
              float* __restrict__ O)
{
    __shared__ _Float16 Kh[KVBLK][LDK];   // K rows (f16)
    __shared__ _Float16 Vt[Dc][LDK];      // Vt[d][pos(key)^swz(d)] = V[key][d]
    __shared__ float    madd[KVBLK];      // additive key mask, log2 domain

    // Balanced map: CU co-residents (bid mod 256 equal) get qt {a,31-a,a,31-a}
    // -> 66 causal tile-iters per CU regardless of a.
    const int bid = blockIdx.x;
    const int g   = bid & 255;
    const int s   = bid >> 8;             // 0..3
    const int gqt = g & 31;
    const int bh  = (g >> 5) + 8 * s;     // 0..31, bijective over (s,g)
    const int qt  = (s & 1) ? (NQT - 1 - gqt) : gqt;
    const int b   = bh >> 4;              // Hc = 16
    const int qb  = qt * QBLK;
    const int nkv = qt + 1;

    const int t    = threadIdx.x;
    const int w    = t >> 6;
    const int lane = t & 63;
    const int l16  = lane & 15;
    const int hi   = lane >> 4;
    const int hi4  = hi * 4;

    const size_t base = (size_t)bh * Sc * Dc;

    // staging map: row = t>>4 (+16i), cols 4*(t&15)..+3  -> coalesced 256B rows
    const int srow = t >> 4;
    const int sd0  = (t & 15) * 4;
    const int ssw  = (t & 7) << 3;        // ((d>>2)&7)<<3 for d = sd0..sd0+3

    float4 kreg[4], vreg[4];
    float  amreg = 0.f;

    auto stage_load = [&](int kvb) {
        #pragma unroll
        for (int i = 0; i < 4; ++i) {
            const size_t gofs = base + (size_t)(kvb + srow + 16 * i) * Dc + sd0;
            kreg[i] = *(const float4*)(K + gofs);
            vreg[i] = *(const float4*)(V + gofs);
        }
        if (t < KVBLK) amreg = AM[(size_t)b * Sc + kvb + t];
    };
    auto stage_write = [&]() {
        #pragma unroll
        for (int i = 0; i < 4; ++i) {
            const int kv = srow + 16 * i;
            half4 kh = { (_Float16)kreg[i].x, (_Float16)kreg[i].y,
                         (_Float16)kreg[i].z, (_Float16)kreg[i].w };
            *(half4*)(&Kh[kv][sd0]) = kh;
            // pos(key): bits {b5,b4b3,b2,b1b0} = {kv5, kv3kv2, kv4, kv1kv0}
            const int pos = ((kv >> 5) << 5) | (((kv >> 2) & 3) << 3)
                          | (((kv >> 4) & 1) << 2) | (kv & 3);
            const int col = pos ^ ssw;
            Vt[sd0 + 0][col] = (_Float16)vreg[i].x;
            Vt[sd0 + 1][col] = (_Float16)vreg[i].y;
            Vt[sd0 + 2][col] = (_Float16)vreg[i].z;
            Vt[sd0 + 3][col] = (_Float16)vreg[i].w;
        }
        if (t < KVBLK) madd[t] = (1.0f - amreg) * (NEGBIG * LOG2E);
    };

    // ---- Q fragments (scale*log2e folded); B-frag: col=l16(q), k=hi*8+j ----
    half8 qfrag[2];
    {
        const float* qp = Q + base + (size_t)(qb + w * 16 + l16) * Dc + hi * 8;
        #pragma unroll
        for (int c = 0; c < 2; ++c) {
            float4 x0 = *(const float4*)(qp + c * 32);
            float4 x1 = *(const float4*)(qp + c * 32 + 4);
            qfrag[c] = (half8){
                (_Float16)(x0.x * SCALE_LOG2E), (_Float16)(x0.y * SCALE_LOG2E),
                (_Float16)(x0.z * SCALE_LOG2E), (_Float16)(x0.w * SCALE_LOG2E),
                (_Float16)(x1.x * SCALE_LOG2E), (_Float16)(x1.y * SCALE_LOG2E),
                (_Float16)(x1.z * SCALE_LOG2E), (_Float16)(x1.w * SCALE_LOG2E) };
        }
    }

    f32x4 o[4];
    #pragma unroll
    for (int dt = 0; dt < 4; ++dt) o[dt] = (f32x4){0.f, 0.f, 0.f, 0.f};
    float m = -INFINITY, l = 0.f;

    stage_load(0);
    stage_write();
    __syncthreads();

    const int qg = qb + w * 16 + l16;     // this lane's q row (S^T domain)

    for (int kvt = 0; kvt < nkv; ++kvt) {
        const int kvb = kvt * KVBLK;
        const bool pref = (kvt + 1 < nkv);
        if (pref) stage_load(kvb + KVBLK);

        // ---- S^T = K . (Q*scale)^T : lane holds S^T[key=nt*16+hi4+r][q=qg] ----
        f32x4 st[4];
        #pragma unroll
        for (int nt = 0; nt < 4; ++nt) {
            st[nt] = (f32x4){0.f, 0.f, 0.f, 0.f};
            #pragma unroll
            for (int c = 0; c < 2; ++c) {
                half8 kf = *(const half8*)(&Kh[nt * 16 + l16][c * 32 + hi * 8]);
                st[nt] = MFMA_F16(kf, qfrag[c], st[nt], 0, 0, 0);
            }
        }

        // ---- masks ----
        const bool diag = (kvt == qt);
        #pragma unroll
        for (int nt = 0; nt < 4; ++nt) {
            const f32x4 mr = *(const f32x4*)(&madd[nt * 16 + hi4]);
            #pragma unroll
            for (int r = 0; r < 4; ++r) {
                float v = st[nt][r] + mr[r];
                if (diag && (kvb + nt * 16 + hi4 + r) > qg) v = NEGBIG;
                st[nt][r] = v;
            }
        }

        // ---- tile max: in-lane tree (16 keys) + cross-hi (2 shuffles) ----
        float pm;
        {
            float a0 = fmaxf(fmaxf(st[0][0], st[0][1]), fmaxf(st[0][2], st[0][3]));
            float a1 = fmaxf(fmaxf(st[1][0], st[1][1]), fmaxf(st[1][2], st[1][3]));
            float a2 = fmaxf(fmaxf(st[2][0], st[2][1]), fmaxf(st[2][2], st[2][3]));
            float a3 = fmaxf(fmaxf(st[3][0], st[3][1]), fmaxf(st[3][2], st[3][3]));
            pm = fmaxf(fmaxf(a0, a1), fmaxf(a2, a3));
        }
        pm = fmaxf(pm, __shfl_xor(pm, 16));
        pm = fmaxf(pm, __shfl_xor(pm, 32));

        // ---- defer-max rescale (skip O-pass when max grew < THR) ----
        if (__any(pm > m + DEFER_THR)) {
            const float mn = fmaxf(m, pm);
            const float f  = exp2f(m - mn);   // first tile: exp2(-inf)=0
            m = mn;
            l *= f;
            #pragma unroll
            for (int r = 0; r < 4; ++r) {
                const float fr = __shfl(f, (lane & 48) + hi4 + r);  // q-row hi4+r
                #pragma unroll
                for (int dt = 0; dt < 4; ++dt) o[dt][r] *= fr;
            }
        }

        // ---- P = exp2(S - m); row-sum in-lane + 2 shuffles ----
        float rs = 0.f;
        #pragma unroll
        for (int nt = 0; nt < 4; ++nt)
            #pragma unroll
            for (int r = 0; r < 4; ++r) {
                const float p = exp2f(st[nt][r] - m);
                st[nt][r] = p;
                rs += p;
            }
        rs += __shfl_xor(rs, 16);
        rs += __shfl_xor(rs, 32);
        l += rs;

        // ---- P -> A-frags, fully lane-local (k-slot->key matches Vt pos()) ----
        half8 pa[2];
        #pragma unroll
        for (int c = 0; c < 2; ++c)
            #pragma unroll
            for (int j = 0; j < 8; ++j)
                pa[c][j] = (_Float16)st[2 * c + (j >> 2)][j & 3];

        // ---- O += P . V ----
        #pragma unroll
        for (int dt = 0; dt < 4; ++dt) {
            const int row = dt * 16 + l16;
            const int sw  = ((row >> 2) & 7) << 3;
            const half8 vf0 = *(const half8*)(&Vt[row][(hi * 8) ^ sw]);
            const half8 vf1 = *(const half8*)(&Vt[row][(32 + hi * 8) ^ sw]);
            o[dt] = MFMA_F16(pa[0], vf0, o[dt], 0, 0, 0);
            o[dt] = MFMA_F16(pa[1], vf1, o[dt], 0, 0, 0);
        }

        if (pref) {
            __syncthreads();      // all waves done reading Kh/Vt
            stage_write();
            __syncthreads();
        }
    }

    // ---- epilogue: redistribute l to O-rows, normalize, store coalesced ----
    float lo[4];
    #pragma unroll
    for (int r = 0; r < 4; ++r)
        lo[r] = __shfl(l, (lane & 48) + hi4 + r);
    float* op = O + base + (size_t)(qb + w * 16 + hi4) * Dc + l16;
    #pragma unroll
    for (int r = 0; r < 4; ++r) {
        const float inv = 1.0f / lo[r];
        #pragma unroll
        for (int dt = 0; dt < 4; ++dt)
            op[(size_t)r * Dc + dt * 16] = o[dt][r] * inv;
    }
}

extern "C" void kernel_launch(void* const* d_in, const int* in_sizes, int n_in,
                              void* d_out, int out_size, void* d_ws, size_t ws_size,
                              hipStream_t stream)
{
    const float* q  = (const float*)d_in[0];
    const float* k  = (const float*)d_in[1];
    const float* v  = (const float*)d_in[2];
    const float* am = (const float*)d_in[3];
    float* out = (float*)d_out;

    dim3 grid(Bc * Hc * NQT);   // 1024 blocks, one (bh,qt) each, balanced per CU
    sdpa_fwd<<<grid, 256, 0, stream>>>(q, k, v, am, out);
}